// Round 1
// baseline (1971.622 us; speedup 1.0000x reference)
//
#include <hip/hip_runtime.h>
#include <math.h>

#define C 28   // channels == dim_head == rank
#define N 64   // tokens per window (8x8)

// LDS layout (float offsets), 4096 floats = 16384 B -> 10 blocks/CU by LDS,
// 16 waves/CU with VGPR<=128 (launch_bounds 128,4). Regions:
//   QTV: QT [28][64] during phaseA..sim, then V [64][28] (overlay)
//   KTA: KT [28][64] during phaseA..sim, then AT32 [32][64] swizzled A-half
#define QTV_OFF 0
#define KTA_OFF 1792
#define SQ_OFF  3840
#define SGK_OFF 3904
#define TH_OFF  3968
#define Z_OFF   4032
#define LDS_FLOATS 4096

__global__ __launch_bounds__(128, 4)
void fa_tiled(const float* __restrict__ x,
              const float* __restrict__ Wqk,   // [56][28]
              const float* __restrict__ Wv,    // [28][28]
              const float* __restrict__ Wout,  // [28][28]
              const float* __restrict__ bout,  // [28]
              const float* __restrict__ Wpcq,  // [28]
              const float* __restrict__ bpcq,  // [1]
              const float* __restrict__ Wpck,  // [28]
              const float* __restrict__ bpck,  // [1]
              const float* __restrict__ Wm1,   // [64]
              const float* __restrict__ Wm2a,  // [64][64]
              const float* __restrict__ Wm2b,  // [64]
              float* __restrict__ out)
{
    __shared__ float S[LDS_FLOATS];

    const int tid = threadIdx.x;       // 0..127 (2 waves per problem)
    const int wv  = tid >> 6;          // wave id: 0 -> q-side, 1 -> k-side
    const int ln  = tid & 63;          // lane in wave == token id in phase A
    const int pid = blockIdx.x;        // 0..8191, one block per problem
    const int win = pid >> 3;
    const int Bi  = pid & 7;
    const int hw = win >> 5, ww = win & 31;
    const int b0 = ln >> 3, b1 = ln & 7;
    const size_t base = ((((size_t)Bi * 256) + (size_t)(hw * 8 + b0)) * 256
                         + (size_t)(ww * 8 + b1)) * C;

    // sim tile coords: 4 rows x 8 cols per lane
    const int ti = tid >> 3;           // 0..15 : rows 4*ti..+4
    const int tj = tid & 7;            // 0..7  : cols 8*tj..+8
    const int gb = ln & 56;            // in-wave base of this lane's tj-group

    // ================= Phase A: q/k projections (lane = token) =============
    float xr[C];
    {
        const float4* p = (const float4*)(x + base);
        #pragma unroll
        for (int i = 0; i < 7; ++i) {
            float4 t = p[i];
            xr[4*i+0] = t.x; xr[4*i+1] = t.y; xr[4*i+2] = t.z; xr[4*i+3] = t.w;
        }
    }

    if (wv == 0) {
        // q -> QT (transposed), sig_q (chains match prior passing kernel)
        float sqa0 = 0.f, sqa1 = 0.f;
        #pragma unroll 2
        for (int d4 = 0; d4 < 7; ++d4) {
            float qq[4];
            #pragma unroll
            for (int t = 0; t < 4; ++t) {
                const int d = 4*d4 + t;
                float a0 = 0.f, a1 = 0.f;
                #pragma unroll
                for (int c = 0; c < C; c += 2) {
                    a0 += Wqk[d*C + c]     * xr[c];
                    a1 += Wqk[d*C + c + 1] * xr[c+1];
                }
                qq[t] = a0 + a1;
                S[QTV_OFF + d*64 + ln] = qq[t];
            }
            sqa0 += qq[0] * Wpcq[4*d4+0];
            sqa1 += qq[1] * Wpcq[4*d4+1];
            sqa0 += qq[2] * Wpcq[4*d4+2];
            sqa1 += qq[3] * Wpcq[4*d4+3];
        }
        S[SQ_OFF + ln] = sqa0 + sqa1 + bpcq[0];
    } else {
        // k -> KT (transposed), sig_k
        float ak = 0.f;
        #pragma unroll 2
        for (int d4 = 0; d4 < 7; ++d4) {
            float kk[4];
            #pragma unroll
            for (int t = 0; t < 4; ++t) {
                const int d = 4*d4 + t;
                float k0 = 0.f, k1 = 0.f;
                #pragma unroll
                for (int c = 0; c < C; c += 2) {
                    k0 += Wqk[(C+d)*C + c]     * xr[c];
                    k1 += Wqk[(C+d)*C + c + 1] * xr[c+1];
                }
                kk[t] = k0 + k1;
                S[KTA_OFF + d*64 + ln] = kk[t];
            }
            ak += kk[0] * Wpck[4*d4+0];
            ak += kk[1] * Wpck[4*d4+1];
            ak += kk[2] * Wpck[4*d4+2];
            ak += kk[3] * Wpck[4*d4+3];
        }
        S[SGK_OFF + ln] = ak + bpck[0];
    }
    __syncthreads();   // B1

    // ============ sim: 4x8 register tile per lane ============
    float acc[8][4];   // acc[cc][rr] = sraw[4ti+rr][8tj+cc]
    #pragma unroll
    for (int cc = 0; cc < 8; ++cc)
        #pragma unroll
        for (int rr = 0; rr < 4; ++rr) acc[cc][rr] = 0.f;

    #pragma unroll 2
    for (int d = 0; d < C; ++d) {
        float4 qa = *(const float4*)&S[QTV_OFF + d*64 + 4*ti];
        float4 ka = *(const float4*)&S[KTA_OFF + d*64 + 8*tj];
        float4 kb = *(const float4*)&S[KTA_OFF + d*64 + 8*tj + 4];
        float q4[4] = {qa.x,qa.y,qa.z,qa.w};
        float k8[8] = {ka.x,ka.y,ka.z,ka.w,kb.x,kb.y,kb.z,kb.w};
        #pragma unroll
        for (int cc = 0; cc < 8; ++cc)
            #pragma unroll
            for (int rr = 0; rr < 4; ++rr)
                acc[cc][rr] += q4[rr] * k8[cc];
    }

    // ---- theta partials (8-col group, strict ascending j; diag excluded),
    //      then sequential ascending-group combine via shfl (exact assoc) ----
    {
        float4 wa = *(const float4*)&Wm1[8*tj];
        float4 wb = *(const float4*)&Wm1[8*tj + 4];
        float w8[8] = {wa.x,wa.y,wa.z,wa.w,wb.x,wb.y,wb.z,wb.w};
        const bool e0 = (4*ti == 8*tj);          // diag at cc == rr
        const bool e4 = (4*ti - 8*tj == 4);      // diag at cc == rr+4
        float th4[4];
        #pragma unroll
        for (int rr = 0; rr < 4; ++rr) {
            float s = 0.f;
            #pragma unroll
            for (int cc = 0; cc < 8; ++cc) {
                float term = acc[cc][rr] * w8[cc];
                if (cc == rr     && e0) term = 0.f;
                if (cc == rr + 4 && e4) term = 0.f;
                s += term;
            }
            float tot = 0.f;
            #pragma unroll
            for (int t = 0; t < 8; ++t) tot += __shfl(s, gb + t, 64);
            th4[rr] = tot;
        }
        #pragma unroll
        for (int r = 0; r < 4; ++r)
            if (tj == r) S[TH_OFF + 4*ti + r] = th4[r];
    }
    __syncthreads();   // B2: QT/KT dead, TH complete

    // ---- MLP2 (both waves redundantly; identical ops -> identical theta) ----
    float theta;
    {
        const float* wrow = Wm2a + ln * N;
        float a0 = 0.f, a1 = 0.f, a2 = 0.f, a3 = 0.f;
        #pragma unroll 4
        for (int i4 = 0; i4 < 16; ++i4) {
            float4 t4 = *(const float4*)&S[TH_OFF + 4*i4];
            float4 w4 = *(const float4*)&wrow[4*i4];
            a0 += t4.x*w4.x; a1 += t4.y*w4.y; a2 += t4.z*w4.z; a3 += t4.w*w4.w;
        }
        float t = (a0 + a1) + (a2 + a3);
        t = (t >= 0.f) ? t : 0.1f * t;
        theta = t * Wm2b[ln];
        #pragma unroll
        for (int off = 32; off > 0; off >>= 1)
            theta += __shfl_xor(theta, off, 64);
    }

    // ---- v -> V (overlays dead QT region), wave-split output dims ----
    if (wv == 0) {
        #pragma unroll
        for (int d4 = 0; d4 < 4; ++d4) {
            float vv[4];
            #pragma unroll
            for (int t = 0; t < 4; ++t) {
                const int d = 4*d4 + t;
                float v0 = 0.f, v1 = 0.f;
                #pragma unroll
                for (int c = 0; c < C; c += 2) {
                    v0 += Wv[d*C + c]     * xr[c];
                    v1 += Wv[d*C + c + 1] * xr[c+1];
                }
                vv[t] = v0 + v1;
            }
            *(float4*)&S[QTV_OFF + ln*C + 4*d4] = make_float4(vv[0],vv[1],vv[2],vv[3]);
        }
    } else {
        #pragma unroll
        for (int d4 = 4; d4 < 7; ++d4) {
            float vv[4];
            #pragma unroll
            for (int t = 0; t < 4; ++t) {
                const int d = 4*d4 + t;
                float v0 = 0.f, v1 = 0.f;
                #pragma unroll
                for (int c = 0; c < C; c += 2) {
                    v0 += Wv[d*C + c]     * xr[c];
                    v1 += Wv[d*C + c + 1] * xr[c+1];
                }
                vv[t] = v0 + v1;
            }
            *(float4*)&S[QTV_OFF + ln*C + 4*d4] = make_float4(vv[0],vv[1],vv[2],vv[3]);
        }
    }

    // ---- Sigma scale (order matches: (sraw*sq)*sgk) ----
    {
        float4 a = *(const float4*)&S[SQ_OFF + 4*ti];
        float sq4[4] = {a.x, a.y, a.z, a.w};
        float4 c0 = *(const float4*)&S[SGK_OFF + 8*tj];
        float4 c1 = *(const float4*)&S[SGK_OFF + 8*tj + 4];
        float sg8[8] = {c0.x,c0.y,c0.z,c0.w,c1.x,c1.y,c1.z,c1.w};
        #pragma unroll
        for (int cc = 0; cc < 8; ++cc)
            #pragma unroll
            for (int rr = 0; rr < 4; ++rr)
                acc[cc][rr] = (acc[cc][rr] * sq4[rr]) * sg8[cc];
    }

    // ---- row max: local over 8 cols then butterfly across tj group ----
    float m4[4];
    #pragma unroll
    for (int rr = 0; rr < 4; ++rr) {
        float mp = -1e30f;
        #pragma unroll
        for (int cc = 0; cc < 8; ++cc) mp = fmaxf(mp, acc[cc][rr]);
        #pragma unroll
        for (int off = 1; off < 8; off <<= 1)
            mp = fmaxf(mp, __shfl_xor(mp, off, 64));
        m4[rr] = mp;
    }

    // ---- exp, Z (sequential ascending-group combine, exact), mask ----
    {
        float z4[4];
        #pragma unroll
        for (int rr = 0; rr < 4; ++rr) {
            float zp = 0.f;
            #pragma unroll
            for (int cc = 0; cc < 8; ++cc) {
                float ss = acc[cc][rr];
                float e = __expf(ss - m4[rr]);
                zp += e;
                acc[cc][rr] = (ss > theta) ? e : 0.f;
            }
            float z = 0.f;
            #pragma unroll
            for (int t = 0; t < 8; ++t) z += __shfl(zp, gb + t, 64);
            z4[rr] = z;
        }
        #pragma unroll
        for (int r = 0; r < 4; ++r)
            if (tj == r) S[Z_OFF + 4*ti + r] = z4[r];
    }

    // ---- A half 1 (cols j<32) -> AT32 over dead KT, rotation-swizzled ----
    if (tj < 4) {
        #pragma unroll
        for (int cc = 0; cc < 8; ++cc) {
            const int j   = 8*tj + cc;          // < 32
            const int rot = j >> 2;
            const int bcc = (4*ti + 8*rot) & 63;
            *(float4*)&S[KTA_OFF + j*64 + bcc] =
                make_float4(acc[cc][0], acc[cc][1], acc[cc][2], acc[cc][3]);
        }
    }
    __syncthreads();   // B3: V, Z, A-half1 ready

    // ============ AV: lane = (row i2, d-half h); strict ascending j ============
    const int i2 = tid >> 1;     // output row 0..63
    const int h  = tid & 1;      // h0: d 0..15, h1: d 16..27 (pav[12..15] unused)
    float pav[16];
    #pragma unroll
    for (int t = 0; t < 16; ++t) pav[t] = 0.f;

    #pragma unroll 2
    for (int jb = 0; jb < 8; ++jb) {
        const int colb = (i2 + 8*jb) & 63;
        #pragma unroll
        for (int cc = 0; cc < 4; ++cc) {
            const int jp = 4*jb + cc;
            const float a = S[KTA_OFF + jp*64 + colb];
            const float* vr = &S[QTV_OFF + jp*C + 16*h];
            float4 v0 = *(const float4*)(vr);
            float4 v1 = *(const float4*)(vr + 4);
            float4 v2 = *(const float4*)(vr + 8);
            float4 v3 = *(const float4*)(vr + 12);   // h1: harmless in-LDS overread
            pav[0] += a*v0.x;  pav[1] += a*v0.y;  pav[2]  += a*v0.z;  pav[3]  += a*v0.w;
            pav[4] += a*v1.x;  pav[5] += a*v1.y;  pav[6]  += a*v1.z;  pav[7]  += a*v1.w;
            pav[8] += a*v2.x;  pav[9] += a*v2.y;  pav[10] += a*v2.z;  pav[11] += a*v2.w;
            pav[12]+= a*v3.x;  pav[13]+= a*v3.y;  pav[14] += a*v3.z;  pav[15] += a*v3.w;
        }
    }
    __syncthreads();   // B4: pass-1 A reads done

    // ---- A half 2 (cols 32..63) ----
    if (tj >= 4) {
        #pragma unroll
        for (int cc = 0; cc < 8; ++cc) {
            const int j   = 8*tj + cc;          // 32..63
            const int jl  = j - 32;
            const int rot = jl >> 2;
            const int bcc = (4*ti + 8*rot) & 63;
            *(float4*)&S[KTA_OFF + jl*64 + bcc] =
                make_float4(acc[cc][0], acc[cc][1], acc[cc][2], acc[cc][3]);
        }
    }
    __syncthreads();   // B5: A-half2 ready

    #pragma unroll 2
    for (int jb = 0; jb < 8; ++jb) {
        const int colb = (i2 + 8*jb) & 63;
        #pragma unroll
        for (int cc = 0; cc < 4; ++cc) {
            const int jp = 4*jb + cc;
            const float a = S[KTA_OFF + jp*64 + colb];
            const float* vr = &S[QTV_OFF + (32 + jp)*C + 16*h];
            float4 v0 = *(const float4*)(vr);
            float4 v1 = *(const float4*)(vr + 4);
            float4 v2 = *(const float4*)(vr + 8);
            float4 v3 = *(const float4*)(vr + 12);
            pav[0] += a*v0.x;  pav[1] += a*v0.y;  pav[2]  += a*v0.z;  pav[3]  += a*v0.w;
            pav[4] += a*v1.x;  pav[5] += a*v1.y;  pav[6]  += a*v1.z;  pav[7]  += a*v1.w;
            pav[8] += a*v2.x;  pav[9] += a*v2.y;  pav[10] += a*v2.z;  pav[11] += a*v2.w;
            pav[12]+= a*v3.x;  pav[13]+= a*v3.y;  pav[14] += a*v3.z;  pav[15] += a*v3.w;
        }
    }

    // normalize by Z (exact 1.0f/Z divide)
    {
        const float rz = 1.0f / S[Z_OFF + i2];
        #pragma unroll
        for (int t = 0; t < 16; ++t) pav[t] *= rz;
    }

    // ============ epilogue: out projection, split by d-half + pair reduce ====
    const int ob0 = i2 >> 3, ob1 = i2 & 7;
    const size_t obase = ((((size_t)Bi * 256) + (size_t)(hw * 8 + ob0)) * 256
                          + (size_t)(ww * 8 + ob1)) * C;
    #pragma unroll
    for (int e4 = 0; e4 < 7; ++e4) {
        float y4[4];
        #pragma unroll
        for (int qd = 0; qd < 4; ++qd) {
            const int e = 4*e4 + qd;
            const float* wr = Wout + e*C + 16*h;
            float4 w0 = *(const float4*)(wr);
            float4 w1 = *(const float4*)(wr + 4);
            float4 w2 = *(const float4*)(wr + 8);
            float pe = w0.x*pav[0] + w0.y*pav[1] + w0.z*pav[2]  + w0.w*pav[3]
                     + w1.x*pav[4] + w1.y*pav[5] + w1.z*pav[6]  + w1.w*pav[7]
                     + w2.x*pav[8] + w2.y*pav[9] + w2.z*pav[10] + w2.w*pav[11];
            if (h == 0) {
                float4 w3 = *(const float4*)(wr + 12);
                pe += w3.x*pav[12] + w3.y*pav[13] + w3.z*pav[14] + w3.w*pav[15];
            }
            pe += __shfl_xor(pe, 1, 64);
            y4[qd] = pe + bout[e];
        }
        if (h == 0)
            *(float4*)(out + obase + 4*e4) = make_float4(y4[0], y4[1], y4[2], y4[3]);
    }
}

extern "C" void kernel_launch(void* const* d_in, const int* in_sizes, int n_in,
                              void* d_out, int out_size, void* d_ws, size_t ws_size,
                              hipStream_t stream) {
    const float* x     = (const float*)d_in[0];
    const float* W_qk  = (const float*)d_in[1];
    const float* W_v   = (const float*)d_in[2];
    const float* W_out = (const float*)d_in[3];
    const float* b_out = (const float*)d_in[4];
    const float* W_pcq = (const float*)d_in[5];
    const float* b_pcq = (const float*)d_in[6];
    const float* W_pck = (const float*)d_in[7];
    const float* b_pck = (const float*)d_in[8];
    const float* W_m1  = (const float*)d_in[9];
    const float* W_m2a = (const float*)d_in[10];
    const float* W_m2b = (const float*)d_in[11];
    float* y = (float*)d_out;

    // 8192 problems, one 128-thread (2-wave) block per problem
    hipLaunchKernelGGL(fa_tiled, dim3(8192), dim3(128), 0, stream,
                       x, W_qk, W_v, W_out, b_out, W_pcq, b_pcq,
                       W_pck, b_pck, W_m1, W_m2a, W_m2b, y);
}

// Round 2
// 273.412 us; speedup vs baseline: 7.2112x; 7.2112x over previous
//
#include <hip/hip_runtime.h>
#include <math.h>

#define C 28   // channels == dim_head == rank
#define N 64   // tokens per window (8x8)

// LDS layout (float offsets). 5648 floats = 22592 B -> 7 blocks/CU (14 waves).
//   QT [28][64] @0, KT [28][64] @1792  (both dead after sim)
//   A-half [32][64] @0 overlays QT+KT-head after sim (two staging passes)
//   V [64][28] @3840 (own region; written in phase A so xr dies early)
#define A_OFF   0
#define QT_OFF  0
#define KT_OFF  1792
#define SQ_OFF  3584
#define SGK_OFF 3648
#define TH_OFF  3712
#define Z_OFF   3776
#define V_OFF   3840
#define LDS_FLOATS 5648   // 3840 + 1792 + 16 pad (h==1 v3 overread stays in-bounds)

__global__ __launch_bounds__(128, 2)
void fa_tiled(const float* __restrict__ x,
              const float* __restrict__ Wqk,   // [56][28]
              const float* __restrict__ Wv,    // [28][28]
              const float* __restrict__ Wout,  // [28][28]
              const float* __restrict__ bout,  // [28]
              const float* __restrict__ Wpcq,  // [28]
              const float* __restrict__ bpcq,  // [1]
              const float* __restrict__ Wpck,  // [28]
              const float* __restrict__ bpck,  // [1]
              const float* __restrict__ Wm1,   // [64]
              const float* __restrict__ Wm2a,  // [64][64]
              const float* __restrict__ Wm2b,  // [64]
              float* __restrict__ out)
{
    __shared__ float S[LDS_FLOATS];

    const int tid = threadIdx.x;       // 0..127 (2 waves per problem)
    const int wv  = tid >> 6;          // wave id: 0 -> q-side, 1 -> k-side
    const int ln  = tid & 63;          // lane in wave == token id in phase A
    const int pid = blockIdx.x;        // 0..8191, one block per problem
    const int win = pid >> 3;
    const int Bi  = pid & 7;
    const int hw = win >> 5, ww = win & 31;
    const int b0 = ln >> 3, b1 = ln & 7;
    const size_t base = ((((size_t)Bi * 256) + (size_t)(hw * 8 + b0)) * 256
                         + (size_t)(ww * 8 + b1)) * C;

    // sim tile coords: 4 rows x 8 cols per lane
    const int ti = tid >> 3;           // 0..15 : rows 4*ti..+4
    const int tj = tid & 7;            // 0..7  : cols 8*tj..+8
    const int gb = ln & 56;            // in-wave base of this lane's tj-group

    // ========== Phase A: q/k/V projections (lane = token); xr dies here =====
    {
        float xr[C];
        {
            const float4* p = (const float4*)(x + base);
            #pragma unroll
            for (int i = 0; i < 7; ++i) {
                float4 t = p[i];
                xr[4*i+0] = t.x; xr[4*i+1] = t.y; xr[4*i+2] = t.z; xr[4*i+3] = t.w;
            }
        }

        if (wv == 0) {
            // q -> QT (transposed), sig_q (chains match prior passing kernel)
            float sqa0 = 0.f, sqa1 = 0.f;
            #pragma unroll 2
            for (int d4 = 0; d4 < 7; ++d4) {
                float qq[4];
                #pragma unroll
                for (int t = 0; t < 4; ++t) {
                    const int d = 4*d4 + t;
                    float a0 = 0.f, a1 = 0.f;
                    #pragma unroll
                    for (int c = 0; c < C; c += 2) {
                        a0 += Wqk[d*C + c]     * xr[c];
                        a1 += Wqk[d*C + c + 1] * xr[c+1];
                    }
                    qq[t] = a0 + a1;
                    S[QT_OFF + d*64 + ln] = qq[t];
                }
                sqa0 += qq[0] * Wpcq[4*d4+0];
                sqa1 += qq[1] * Wpcq[4*d4+1];
                sqa0 += qq[2] * Wpcq[4*d4+2];
                sqa1 += qq[3] * Wpcq[4*d4+3];
            }
            S[SQ_OFF + ln] = sqa0 + sqa1 + bpcq[0];
            // V dims d = 0..15
            #pragma unroll
            for (int d4 = 0; d4 < 4; ++d4) {
                float vv[4];
                #pragma unroll
                for (int t = 0; t < 4; ++t) {
                    const int d = 4*d4 + t;
                    float v0 = 0.f, v1 = 0.f;
                    #pragma unroll
                    for (int c = 0; c < C; c += 2) {
                        v0 += Wv[d*C + c]     * xr[c];
                        v1 += Wv[d*C + c + 1] * xr[c+1];
                    }
                    vv[t] = v0 + v1;
                }
                *(float4*)&S[V_OFF + ln*C + 4*d4] = make_float4(vv[0],vv[1],vv[2],vv[3]);
            }
        } else {
            // k -> KT (transposed), sig_k
            float ak = 0.f;
            #pragma unroll 2
            for (int d4 = 0; d4 < 7; ++d4) {
                float kk[4];
                #pragma unroll
                for (int t = 0; t < 4; ++t) {
                    const int d = 4*d4 + t;
                    float k0 = 0.f, k1 = 0.f;
                    #pragma unroll
                    for (int c = 0; c < C; c += 2) {
                        k0 += Wqk[(C+d)*C + c]     * xr[c];
                        k1 += Wqk[(C+d)*C + c + 1] * xr[c+1];
                    }
                    kk[t] = k0 + k1;
                    S[KT_OFF + d*64 + ln] = kk[t];
                }
                ak += kk[0] * Wpck[4*d4+0];
                ak += kk[1] * Wpck[4*d4+1];
                ak += kk[2] * Wpck[4*d4+2];
                ak += kk[3] * Wpck[4*d4+3];
            }
            S[SGK_OFF + ln] = ak + bpck[0];
            // V dims d = 16..27
            #pragma unroll
            for (int d4 = 4; d4 < 7; ++d4) {
                float vv[4];
                #pragma unroll
                for (int t = 0; t < 4; ++t) {
                    const int d = 4*d4 + t;
                    float v0 = 0.f, v1 = 0.f;
                    #pragma unroll
                    for (int c = 0; c < C; c += 2) {
                        v0 += Wv[d*C + c]     * xr[c];
                        v1 += Wv[d*C + c + 1] * xr[c+1];
                    }
                    vv[t] = v0 + v1;
                }
                *(float4*)&S[V_OFF + ln*C + 4*d4] = make_float4(vv[0],vv[1],vv[2],vv[3]);
            }
        }
    }
    __syncthreads();   // B1: QT, KT, V, SQ, SGK ready

    // ============ sim: 4x8 register tile per lane ============
    float acc[8][4];   // acc[cc][rr] = sraw[4ti+rr][8tj+cc]
    #pragma unroll
    for (int cc = 0; cc < 8; ++cc)
        #pragma unroll
        for (int rr = 0; rr < 4; ++rr) acc[cc][rr] = 0.f;

    #pragma unroll 2
    for (int d = 0; d < C; ++d) {
        float4 qa = *(const float4*)&S[QT_OFF + d*64 + 4*ti];
        float4 ka = *(const float4*)&S[KT_OFF + d*64 + 8*tj];
        float4 kb = *(const float4*)&S[KT_OFF + d*64 + 8*tj + 4];
        float q4[4] = {qa.x,qa.y,qa.z,qa.w};
        float k8[8] = {ka.x,ka.y,ka.z,ka.w,kb.x,kb.y,kb.z,kb.w};
        #pragma unroll
        for (int cc = 0; cc < 8; ++cc)
            #pragma unroll
            for (int rr = 0; rr < 4; ++rr)
                acc[cc][rr] += q4[rr] * k8[cc];
    }

    // ---- theta partials (8-col group, strict ascending j; diag excluded),
    //      then sequential ascending-group combine via shfl (exact assoc) ----
    {
        float4 wa = *(const float4*)&Wm1[8*tj];
        float4 wb = *(const float4*)&Wm1[8*tj + 4];
        float w8[8] = {wa.x,wa.y,wa.z,wa.w,wb.x,wb.y,wb.z,wb.w};
        const bool e0 = (4*ti == 8*tj);          // diag at cc == rr
        const bool e4 = (4*ti - 8*tj == 4);      // diag at cc == rr+4
        float th4[4];
        #pragma unroll
        for (int rr = 0; rr < 4; ++rr) {
            float s = 0.f;
            #pragma unroll
            for (int cc = 0; cc < 8; ++cc) {
                float term = acc[cc][rr] * w8[cc];
                if (cc == rr     && e0) term = 0.f;
                if (cc == rr + 4 && e4) term = 0.f;
                s += term;
            }
            float tot = 0.f;
            #pragma unroll
            for (int t = 0; t < 8; ++t) tot += __shfl(s, gb + t, 64);
            th4[rr] = tot;
        }
        #pragma unroll
        for (int r = 0; r < 4; ++r)
            if (tj == r) S[TH_OFF + 4*ti + r] = th4[r];
    }
    __syncthreads();   // B2: QT/KT reads done, TH complete

    // ---- MLP2 (both waves redundantly; identical ops -> identical theta) ----
    float theta;
    {
        const float* wrow = Wm2a + ln * N;
        float a0 = 0.f, a1 = 0.f, a2 = 0.f, a3 = 0.f;
        #pragma unroll 4
        for (int i4 = 0; i4 < 16; ++i4) {
            float4 t4 = *(const float4*)&S[TH_OFF + 4*i4];
            float4 w4 = *(const float4*)&wrow[4*i4];
            a0 += t4.x*w4.x; a1 += t4.y*w4.y; a2 += t4.z*w4.z; a3 += t4.w*w4.w;
        }
        float t = (a0 + a1) + (a2 + a3);
        t = (t >= 0.f) ? t : 0.1f * t;
        theta = t * Wm2b[ln];
        #pragma unroll
        for (int off = 32; off > 0; off >>= 1)
            theta += __shfl_xor(theta, off, 64);
    }

    // ---- Sigma scale (order matches: (sraw*sq)*sgk) ----
    {
        float4 a = *(const float4*)&S[SQ_OFF + 4*ti];
        float sq4[4] = {a.x, a.y, a.z, a.w};
        float4 c0 = *(const float4*)&S[SGK_OFF + 8*tj];
        float4 c1 = *(const float4*)&S[SGK_OFF + 8*tj + 4];
        float sg8[8] = {c0.x,c0.y,c0.z,c0.w,c1.x,c1.y,c1.z,c1.w};
        #pragma unroll
        for (int cc = 0; cc < 8; ++cc)
            #pragma unroll
            for (int rr = 0; rr < 4; ++rr)
                acc[cc][rr] = (acc[cc][rr] * sq4[rr]) * sg8[cc];
    }

    // ---- row max: local over 8 cols then butterfly across tj group ----
    float m4[4];
    #pragma unroll
    for (int rr = 0; rr < 4; ++rr) {
        float mp = -1e30f;
        #pragma unroll
        for (int cc = 0; cc < 8; ++cc) mp = fmaxf(mp, acc[cc][rr]);
        #pragma unroll
        for (int off = 1; off < 8; off <<= 1)
            mp = fmaxf(mp, __shfl_xor(mp, off, 64));
        m4[rr] = mp;
    }

    // ---- exp, Z (sequential ascending-group combine, exact), mask ----
    {
        float z4[4];
        #pragma unroll
        for (int rr = 0; rr < 4; ++rr) {
            float zp = 0.f;
            #pragma unroll
            for (int cc = 0; cc < 8; ++cc) {
                float ss = acc[cc][rr];
                float e = __expf(ss - m4[rr]);
                zp += e;
                acc[cc][rr] = (ss > theta) ? e : 0.f;
            }
            float z = 0.f;
            #pragma unroll
            for (int t = 0; t < 8; ++t) z += __shfl(zp, gb + t, 64);
            z4[rr] = z;
        }
        #pragma unroll
        for (int r = 0; r < 4; ++r)
            if (tj == r) S[Z_OFF + 4*ti + r] = z4[r];
    }

    // ---- A half 1 (cols j<32) -> [32][64] over dead QT/KT, rotation-swizzled
    if (tj < 4) {
        #pragma unroll
        for (int cc = 0; cc < 8; ++cc) {
            const int j   = 8*tj + cc;          // < 32
            const int rot = j >> 2;
            const int bcc = (4*ti + 8*rot) & 63;
            *(float4*)&S[A_OFF + j*64 + bcc] =
                make_float4(acc[cc][0], acc[cc][1], acc[cc][2], acc[cc][3]);
        }
    }
    __syncthreads();   // B3: V, Z, A-half1 ready

    // ============ AV: lane = (row i2, d-half h); strict ascending j ==========
    const int i2 = tid >> 1;     // output row 0..63
    const int h  = tid & 1;      // h0: d 0..15, h1: d 16..27 (pav[12..15] unused)
    float pav[16];
    #pragma unroll
    for (int t = 0; t < 16; ++t) pav[t] = 0.f;

    #pragma unroll 2
    for (int jb = 0; jb < 8; ++jb) {
        const int colb = (i2 + 8*jb) & 63;
        #pragma unroll
        for (int cc = 0; cc < 4; ++cc) {
            const int jp = 4*jb + cc;
            const float a = S[A_OFF + jp*64 + colb];
            const float* vr = &S[V_OFF + jp*C + 16*h];
            float4 v0 = *(const float4*)(vr);
            float4 v1 = *(const float4*)(vr + 4);
            float4 v2 = *(const float4*)(vr + 8);
            float4 v3 = *(const float4*)(vr + 12);   // h1: in-pad overread, unused
            pav[0] += a*v0.x;  pav[1] += a*v0.y;  pav[2]  += a*v0.z;  pav[3]  += a*v0.w;
            pav[4] += a*v1.x;  pav[5] += a*v1.y;  pav[6]  += a*v1.z;  pav[7]  += a*v1.w;
            pav[8] += a*v2.x;  pav[9] += a*v2.y;  pav[10] += a*v2.z;  pav[11] += a*v2.w;
            pav[12]+= a*v3.x;  pav[13]+= a*v3.y;  pav[14] += a*v3.z;  pav[15] += a*v3.w;
        }
    }
    __syncthreads();   // B4: pass-1 A reads done

    // ---- A half 2 (cols 32..63) ----
    if (tj >= 4) {
        #pragma unroll
        for (int cc = 0; cc < 8; ++cc) {
            const int j   = 8*tj + cc;          // 32..63
            const int jl  = j - 32;
            const int rot = jl >> 2;
            const int bcc = (4*ti + 8*rot) & 63;
            *(float4*)&S[A_OFF + jl*64 + bcc] =
                make_float4(acc[cc][0], acc[cc][1], acc[cc][2], acc[cc][3]);
        }
    }
    __syncthreads();   // B5: A-half2 ready

    #pragma unroll 2
    for (int jb = 0; jb < 8; ++jb) {
        const int colb = (i2 + 8*jb) & 63;
        #pragma unroll
        for (int cc = 0; cc < 4; ++cc) {
            const int jp = 4*jb + cc;
            const float a = S[A_OFF + jp*64 + colb];
            const float* vr = &S[V_OFF + (32 + jp)*C + 16*h];
            float4 v0 = *(const float4*)(vr);
            float4 v1 = *(const float4*)(vr + 4);
            float4 v2 = *(const float4*)(vr + 8);
            float4 v3 = *(const float4*)(vr + 12);
            pav[0] += a*v0.x;  pav[1] += a*v0.y;  pav[2]  += a*v0.z;  pav[3]  += a*v0.w;
            pav[4] += a*v1.x;  pav[5] += a*v1.y;  pav[6]  += a*v1.z;  pav[7]  += a*v1.w;
            pav[8] += a*v2.x;  pav[9] += a*v2.y;  pav[10] += a*v2.z;  pav[11] += a*v2.w;
            pav[12]+= a*v3.x;  pav[13]+= a*v3.y;  pav[14] += a*v3.z;  pav[15] += a*v3.w;
        }
    }

    // normalize by Z (exact 1.0f/Z divide)
    {
        const float rz = 1.0f / S[Z_OFF + i2];
        #pragma unroll
        for (int t = 0; t < 16; ++t) pav[t] *= rz;
    }

    // ============ epilogue: out projection, split by d-half + pair reduce ====
    const int ob0 = i2 >> 3, ob1 = i2 & 7;
    const size_t obase = ((((size_t)Bi * 256) + (size_t)(hw * 8 + ob0)) * 256
                          + (size_t)(ww * 8 + ob1)) * C;
    #pragma unroll
    for (int e4 = 0; e4 < 7; ++e4) {
        float y4[4];
        #pragma unroll
        for (int qd = 0; qd < 4; ++qd) {
            const int e = 4*e4 + qd;
            const float* wr = Wout + e*C + 16*h;
            float4 w0 = *(const float4*)(wr);
            float4 w1 = *(const float4*)(wr + 4);
            float4 w2 = *(const float4*)(wr + 8);
            float pe = w0.x*pav[0] + w0.y*pav[1] + w0.z*pav[2]  + w0.w*pav[3]
                     + w1.x*pav[4] + w1.y*pav[5] + w1.z*pav[6]  + w1.w*pav[7]
                     + w2.x*pav[8] + w2.y*pav[9] + w2.z*pav[10] + w2.w*pav[11];
            if (h == 0) {
                float4 w3 = *(const float4*)(wr + 12);
                pe += w3.x*pav[12] + w3.y*pav[13] + w3.z*pav[14] + w3.w*pav[15];
            }
            pe += __shfl_xor(pe, 1, 64);
            y4[qd] = pe + bout[e];
        }
        if (h == 0)
            *(float4*)(out + obase + 4*e4) = make_float4(y4[0], y4[1], y4[2], y4[3]);
    }
}

extern "C" void kernel_launch(void* const* d_in, const int* in_sizes, int n_in,
                              void* d_out, int out_size, void* d_ws, size_t ws_size,
                              hipStream_t stream) {
    const float* x     = (const float*)d_in[0];
    const float* W_qk  = (const float*)d_in[1];
    const float* W_v   = (const float*)d_in[2];
    const float* W_out = (const float*)d_in[3];
    const float* b_out = (const float*)d_in[4];
    const float* W_pcq = (const float*)d_in[5];
    const float* b_pcq = (const float*)d_in[6];
    const float* W_pck = (const float*)d_in[7];
    const float* b_pck = (const float*)d_in[8];
    const float* W_m1  = (const float*)d_in[9];
    const float* W_m2a = (const float*)d_in[10];
    const float* W_m2b = (const float*)d_in[11];
    float* y = (float*)d_out;

    // 8192 problems, one 128-thread (2-wave) block per problem
    hipLaunchKernelGGL(fa_tiled, dim3(8192), dim3(128), 0, stream,
                       x, W_qk, W_v, W_out, b_out, W_pcq, b_pcq,
                       W_pck, b_pck, W_m1, W_m2a, W_m2b, y);
}

// Round 3
// 227.165 us; speedup vs baseline: 8.6792x; 1.2036x over previous
//
#include <hip/hip_runtime.h>
#include <math.h>

#define C 28   // channels == dim_head == rank
#define N 64   // tokens per window (8x8)

// LDS layout (float offsets). 6080 floats = 24320 B -> 6 blocks/CU (12 waves).
// Phase 1: QT [28][64] @0, KT [28][64] @1792 (dead after sim/B2)
// Phase 2: A  = two per-wave halves [64 j][32 i] @0 and @2048 (overlay QT/KT)
//          OT = per-wave [32][28] overlays own A half after AV reads done
// Scalars SQ/SGK/TH live OUTSIDE the A range (cross-wave race otherwise).
#define A_OFF   0
#define QT_OFF  0
#define KT_OFF  1792
#define SQ_OFF  4096
#define SGK_OFF 4160
#define TH_OFF  4224
#define V_OFF   4288   // [64][28]
#define LDS_FLOATS 6080

__global__ __launch_bounds__(128, 2)
void fa_tiled(const float* __restrict__ x,
              const float* __restrict__ Wqk,   // [56][28]
              const float* __restrict__ Wv,    // [28][28]
              const float* __restrict__ Wout,  // [28][28]
              const float* __restrict__ bout,  // [28]
              const float* __restrict__ Wpcq,  // [28]
              const float* __restrict__ bpcq,  // [1]
              const float* __restrict__ Wpck,  // [28]
              const float* __restrict__ bpck,  // [1]
              const float* __restrict__ Wm1,   // [64]
              const float* __restrict__ Wm2a,  // [64][64]
              const float* __restrict__ Wm2b,  // [64]
              float* __restrict__ out)
{
    __shared__ float S[LDS_FLOATS];

    const int tid = threadIdx.x;       // 0..127 (2 waves per problem)
    const int wv  = tid >> 6;          // wave id: 0 -> q-side, 1 -> k-side
    const int ln  = tid & 63;          // lane in wave == token id in phase A
    const int pid = blockIdx.x;        // 0..8191, one block per problem
    const int win = pid >> 3;
    const int Bi  = pid & 7;
    const int hw = win >> 5, ww = win & 31;
    const int b0 = ln >> 3, b1 = ln & 7;
    const size_t base = ((((size_t)Bi * 256) + (size_t)(hw * 8 + b0)) * 256
                         + (size_t)(ww * 8 + b1)) * C;

    // sim tile coords: 4 rows x 8 cols per lane; rows 4*ti..+4 are THIS lane's
    const int ti = tid >> 3;           // 0..15 (global row group)
    const int tj = tid & 7;            // 0..7  (col group, j = 8*tj+cc)
    const int rg = ti & 7;             // wave-local row group 0..7
    const int gb = ln & 56;            // in-wave base of this lane's tj-group

    // ========== Phase A: q/k/V projections (lane = token); xr dies here =====
    {
        float xr[C];
        {
            const float4* p = (const float4*)(x + base);
            #pragma unroll
            for (int i = 0; i < 7; ++i) {
                float4 t = p[i];
                xr[4*i+0] = t.x; xr[4*i+1] = t.y; xr[4*i+2] = t.z; xr[4*i+3] = t.w;
            }
        }

        if (wv == 0) {
            // q -> QT (transposed), sig_q (chains match prior passing kernel)
            float sqa0 = 0.f, sqa1 = 0.f;
            #pragma unroll 2
            for (int d4 = 0; d4 < 7; ++d4) {
                float qq[4];
                #pragma unroll
                for (int t = 0; t < 4; ++t) {
                    const int d = 4*d4 + t;
                    float a0 = 0.f, a1 = 0.f;
                    #pragma unroll
                    for (int c = 0; c < C; c += 2) {
                        a0 += Wqk[d*C + c]     * xr[c];
                        a1 += Wqk[d*C + c + 1] * xr[c+1];
                    }
                    qq[t] = a0 + a1;
                    S[QT_OFF + d*64 + ln] = qq[t];
                }
                sqa0 += qq[0] * Wpcq[4*d4+0];
                sqa1 += qq[1] * Wpcq[4*d4+1];
                sqa0 += qq[2] * Wpcq[4*d4+2];
                sqa1 += qq[3] * Wpcq[4*d4+3];
            }
            S[SQ_OFF + ln] = sqa0 + sqa1 + bpcq[0];
            // V dims d = 0..15
            #pragma unroll
            for (int d4 = 0; d4 < 4; ++d4) {
                float vv[4];
                #pragma unroll
                for (int t = 0; t < 4; ++t) {
                    const int d = 4*d4 + t;
                    float v0 = 0.f, v1 = 0.f;
                    #pragma unroll
                    for (int c = 0; c < C; c += 2) {
                        v0 += Wv[d*C + c]     * xr[c];
                        v1 += Wv[d*C + c + 1] * xr[c+1];
                    }
                    vv[t] = v0 + v1;
                }
                *(float4*)&S[V_OFF + ln*C + 4*d4] = make_float4(vv[0],vv[1],vv[2],vv[3]);
            }
        } else {
            // k -> KT (transposed), sig_k
            float ak = 0.f;
            #pragma unroll 2
            for (int d4 = 0; d4 < 7; ++d4) {
                float kk[4];
                #pragma unroll
                for (int t = 0; t < 4; ++t) {
                    const int d = 4*d4 + t;
                    float k0 = 0.f, k1 = 0.f;
                    #pragma unroll
                    for (int c = 0; c < C; c += 2) {
                        k0 += Wqk[(C+d)*C + c]     * xr[c];
                        k1 += Wqk[(C+d)*C + c + 1] * xr[c+1];
                    }
                    kk[t] = k0 + k1;
                    S[KT_OFF + d*64 + ln] = kk[t];
                }
                ak += kk[0] * Wpck[4*d4+0];
                ak += kk[1] * Wpck[4*d4+1];
                ak += kk[2] * Wpck[4*d4+2];
                ak += kk[3] * Wpck[4*d4+3];
            }
            S[SGK_OFF + ln] = ak + bpck[0];
            // V dims d = 16..27
            #pragma unroll
            for (int d4 = 4; d4 < 7; ++d4) {
                float vv[4];
                #pragma unroll
                for (int t = 0; t < 4; ++t) {
                    const int d = 4*d4 + t;
                    float v0 = 0.f, v1 = 0.f;
                    #pragma unroll
                    for (int c = 0; c < C; c += 2) {
                        v0 += Wv[d*C + c]     * xr[c];
                        v1 += Wv[d*C + c + 1] * xr[c+1];
                    }
                    vv[t] = v0 + v1;
                }
                *(float4*)&S[V_OFF + ln*C + 4*d4] = make_float4(vv[0],vv[1],vv[2],vv[3]);
            }
        }
    }
    __syncthreads();   // B1: QT, KT, V, SQ, SGK ready

    // ============ sim: 4x8 register tile per lane ============
    float acc[8][4];   // acc[cc][rr] = sraw[4ti+rr][8tj+cc]
    #pragma unroll
    for (int cc = 0; cc < 8; ++cc)
        #pragma unroll
        for (int rr = 0; rr < 4; ++rr) acc[cc][rr] = 0.f;

    #pragma unroll 2
    for (int d = 0; d < C; ++d) {
        float4 qa = *(const float4*)&S[QT_OFF + d*64 + 4*ti];
        float4 ka = *(const float4*)&S[KT_OFF + d*64 + 8*tj];
        float4 kb = *(const float4*)&S[KT_OFF + d*64 + 8*tj + 4];
        float q4[4] = {qa.x,qa.y,qa.z,qa.w};
        float k8[8] = {ka.x,ka.y,ka.z,ka.w,kb.x,kb.y,kb.z,kb.w};
        #pragma unroll
        for (int cc = 0; cc < 8; ++cc)
            #pragma unroll
            for (int rr = 0; rr < 4; ++rr)
                acc[cc][rr] += q4[rr] * k8[cc];
    }

    // ---- theta partials (8-col group, strict ascending j; diag excluded),
    //      then sequential ascending-group combine via shfl (exact assoc) ----
    {
        float4 wa = *(const float4*)&Wm1[8*tj];
        float4 wb = *(const float4*)&Wm1[8*tj + 4];
        float w8[8] = {wa.x,wa.y,wa.z,wa.w,wb.x,wb.y,wb.z,wb.w};
        const bool e0 = (4*ti == 8*tj);          // diag at cc == rr
        const bool e4 = (4*ti - 8*tj == 4);      // diag at cc == rr+4
        float th4[4];
        #pragma unroll
        for (int rr = 0; rr < 4; ++rr) {
            float s = 0.f;
            #pragma unroll
            for (int cc = 0; cc < 8; ++cc) {
                float term = acc[cc][rr] * w8[cc];
                if (cc == rr     && e0) term = 0.f;
                if (cc == rr + 4 && e4) term = 0.f;
                s += term;
            }
            float tot = 0.f;
            #pragma unroll
            for (int t = 0; t < 8; ++t) tot += __shfl(s, gb + t, 64);
            th4[rr] = tot;
        }
        #pragma unroll
        for (int r = 0; r < 4; ++r)
            if (tj == r) S[TH_OFF + 4*ti + r] = th4[r];
    }
    __syncthreads();   // B2: QT/KT reads done, TH complete

    // ---- MLP2 (both waves redundantly; identical ops -> identical theta) ----
    float theta;
    {
        const float* wrow = Wm2a + ln * N;
        float a0 = 0.f, a1 = 0.f, a2 = 0.f, a3 = 0.f;
        #pragma unroll 4
        for (int i4 = 0; i4 < 16; ++i4) {
            float4 t4 = *(const float4*)&S[TH_OFF + 4*i4];
            float4 w4 = *(const float4*)&wrow[4*i4];
            a0 += t4.x*w4.x; a1 += t4.y*w4.y; a2 += t4.z*w4.z; a3 += t4.w*w4.w;
        }
        float t = (a0 + a1) + (a2 + a3);
        t = (t >= 0.f) ? t : 0.1f * t;
        theta = t * Wm2b[ln];
        #pragma unroll
        for (int off = 32; off > 0; off >>= 1)
            theta += __shfl_xor(theta, off, 64);
    }

    // ---- Sigma scale (order matches: (sraw*sq)*sgk) ----
    {
        float4 a = *(const float4*)&S[SQ_OFF + 4*ti];
        float sq4[4] = {a.x, a.y, a.z, a.w};
        float4 c0 = *(const float4*)&S[SGK_OFF + 8*tj];
        float4 c1 = *(const float4*)&S[SGK_OFF + 8*tj + 4];
        float sg8[8] = {c0.x,c0.y,c0.z,c0.w,c1.x,c1.y,c1.z,c1.w};
        #pragma unroll
        for (int cc = 0; cc < 8; ++cc)
            #pragma unroll
            for (int rr = 0; rr < 4; ++rr)
                acc[cc][rr] = (acc[cc][rr] * sq4[rr]) * sg8[cc];
    }

    // ---- row max: local over 8 cols then butterfly across tj group ----
    float m4[4];
    #pragma unroll
    for (int rr = 0; rr < 4; ++rr) {
        float mp = -1e30f;
        #pragma unroll
        for (int cc = 0; cc < 8; ++cc) mp = fmaxf(mp, acc[cc][rr]);
        #pragma unroll
        for (int off = 1; off < 8; off <<= 1)
            mp = fmaxf(mp, __shfl_xor(mp, off, 64));
        m4[rr] = mp;
    }

    // ---- exp, Z (sequential ascending-group combine, exact), mask in regs ----
    float z4[4];
    #pragma unroll
    for (int rr = 0; rr < 4; ++rr) {
        float zp = 0.f;
        #pragma unroll
        for (int cc = 0; cc < 8; ++cc) {
            float ss = acc[cc][rr];
            float e = __expf(ss - m4[rr]);
            zp += e;
            acc[cc][rr] = (ss > theta) ? e : 0.f;
        }
        float z = 0.f;
        #pragma unroll
        for (int t = 0; t < 8; ++t) z += __shfl(zp, gb + t, 64);
        z4[rr] = z;
    }

    // ---- stage this wave's A half: Aw[j][32], rotation-swizzled by j>>3 ----
    // write addr = j*32 + ((4*rg + 4*(j>>3)) & 31); in-wave producer/consumer
    // only (each wave reads back only its own half) -> no barrier needed.
    float* Aw = &S[A_OFF + 2048*wv];
    #pragma unroll
    for (int cc = 0; cc < 8; ++cc) {
        const int j = 8*tj + cc;
        *(float4*)&Aw[j*32 + ((4*rg + 4*tj) & 31)] =
            make_float4(acc[cc][0], acc[cc][1], acc[cc][2], acc[cc][3]);
    }

    // ============ AV: lane = (rg, dg); rows 32*wv+4*rg..+4, d 4*dgc..+4 ======
    // per j: 1 A-b128 + 1 V-b128 -> 16 FMA. Ascending j (exact association).
    const int dg  = tj;
    const int dgc = (dg < 7) ? dg : 6;   // dg==7 duplicates dg==6, write masked
    float pav0[4] = {0,0,0,0}, pav1[4] = {0,0,0,0};
    float pav2[4] = {0,0,0,0}, pav3[4] = {0,0,0,0};

    #pragma unroll 8
    for (int j = 0; j < 64; ++j) {
        float4 a4 = *(const float4*)&Aw[j*32 + ((4*rg + 4*(j>>3)) & 31)];
        float4 v4 = *(const float4*)&S[V_OFF + j*C + 4*dgc];
        pav0[0] += a4.x*v4.x; pav0[1] += a4.x*v4.y; pav0[2] += a4.x*v4.z; pav0[3] += a4.x*v4.w;
        pav1[0] += a4.y*v4.x; pav1[1] += a4.y*v4.y; pav1[2] += a4.y*v4.z; pav1[3] += a4.y*v4.w;
        pav2[0] += a4.z*v4.x; pav2[1] += a4.z*v4.y; pav2[2] += a4.z*v4.z; pav2[3] += a4.z*v4.w;
        pav3[0] += a4.w*v4.x; pav3[1] += a4.w*v4.y; pav3[2] += a4.w*v4.z; pav3[3] += a4.w*v4.w;
    }

    // normalize by Z (exact 1.0f/Z divide; z4 already lives in this lane)
    {
        float rz0 = 1.0f / z4[0], rz1 = 1.0f / z4[1];
        float rz2 = 1.0f / z4[2], rz3 = 1.0f / z4[3];
        #pragma unroll
        for (int t = 0; t < 4; ++t) {
            pav0[t] *= rz0; pav1[t] *= rz1; pav2[t] *= rz2; pav3[t] *= rz3;
        }
    }

    // ---- OT: overlay own A half (all own-A reads done; in-wave order) ------
    if (dg < 7) {
        *(float4*)&Aw[(4*rg+0)*C + 4*dg] = make_float4(pav0[0],pav0[1],pav0[2],pav0[3]);
        *(float4*)&Aw[(4*rg+1)*C + 4*dg] = make_float4(pav1[0],pav1[1],pav1[2],pav1[3]);
        *(float4*)&Aw[(4*rg+2)*C + 4*dg] = make_float4(pav2[0],pav2[1],pav2[2],pav2[3]);
        *(float4*)&Aw[(4*rg+3)*C + 4*dg] = make_float4(pav3[0],pav3[1],pav3[2],pav3[3]);
    }
    __syncthreads();   // B3: both OT halves ready

    // ============ epilogue: out projection, lane = token, e-split by wave ====
    float o[C];
    {
        const float* orow = &S[A_OFF + 2048*(ln >> 5) + (ln & 31)*C];
        #pragma unroll
        for (int i = 0; i < 7; ++i) {
            float4 t = *(const float4*)(orow + 4*i);
            o[4*i+0] = t.x; o[4*i+1] = t.y; o[4*i+2] = t.z; o[4*i+3] = t.w;
        }
    }
    if (wv == 0) {       // e = 0..15
        float y[16];
        #pragma unroll 2
        for (int e4 = 0; e4 < 4; ++e4) {
            #pragma unroll
            for (int t = 0; t < 4; ++t) {
                const int e = 4*e4 + t;
                float a0 = 0.f, a1 = 0.f;
                #pragma unroll
                for (int d = 0; d < C; d += 2) {
                    a0 += Wout[e*C + d]     * o[d];
                    a1 += Wout[e*C + d + 1] * o[d+1];
                }
                y[e] = (a0 + a1) + bout[e];
            }
        }
        float4* yp = (float4*)(out + base);
        #pragma unroll
        for (int i = 0; i < 4; ++i)
            yp[i] = make_float4(y[4*i+0], y[4*i+1], y[4*i+2], y[4*i+3]);
    } else {             // e = 16..27
        float y[12];
        #pragma unroll 2
        for (int e4 = 0; e4 < 3; ++e4) {
            #pragma unroll
            for (int t = 0; t < 4; ++t) {
                const int e = 16 + 4*e4 + t;
                float a0 = 0.f, a1 = 0.f;
                #pragma unroll
                for (int d = 0; d < C; d += 2) {
                    a0 += Wout[e*C + d]     * o[d];
                    a1 += Wout[e*C + d + 1] * o[d+1];
                }
                y[4*e4+t] = (a0 + a1) + bout[e];
            }
        }
        float4* yp = (float4*)(out + base + 16);
        #pragma unroll
        for (int i = 0; i < 3; ++i)
            yp[i] = make_float4(y[4*i+0], y[4*i+1], y[4*i+2], y[4*i+3]);
    }
}

extern "C" void kernel_launch(void* const* d_in, const int* in_sizes, int n_in,
                              void* d_out, int out_size, void* d_ws, size_t ws_size,
                              hipStream_t stream) {
    const float* x     = (const float*)d_in[0];
    const float* W_qk  = (const float*)d_in[1];
    const float* W_v   = (const float*)d_in[2];
    const float* W_out = (const float*)d_in[3];
    const float* b_out = (const float*)d_in[4];
    const float* W_pcq = (const float*)d_in[5];
    const float* b_pcq = (const float*)d_in[6];
    const float* W_pck = (const float*)d_in[7];
    const float* b_pck = (const float*)d_in[8];
    const float* W_m1  = (const float*)d_in[9];
    const float* W_m2a = (const float*)d_in[10];
    const float* W_m2b = (const float*)d_in[11];
    float* y = (float*)d_out;

    // 8192 problems, one 128-thread (2-wave) block per problem
    hipLaunchKernelGGL(fa_tiled, dim3(8192), dim3(128), 0, stream,
                       x, W_qk, W_v, W_out, b_out, W_pcq, b_pcq,
                       W_pck, b_pck, W_m1, W_m2a, W_m2b, y);
}